// Round 7
// baseline (1122.186 us; speedup 1.0000x reference)
//
#include <hip/hip_runtime.h>
#include <hip/hip_bf16.h>
#include <math.h>

// Problem constants
#define B_   32
#define S_   512
#define V_   30000
#define E_   300
#define H_   200
#define NH_  4
#define ENC_ 400
#define G4_  800     // 4*H
#define NEGV  (-1e9f)
#define SCALE_ 1000.0f

typedef _Float16 half2v __attribute__((ext_vector_type(2)));
typedef _Float16 f16x8  __attribute__((ext_vector_type(8)));
typedef float    f32x4  __attribute__((ext_vector_type(4)));

#if defined(__has_builtin)
#if __has_builtin(__builtin_amdgcn_fdot2)
#define FDOT2(a,b,c) __builtin_amdgcn_fdot2((a),(b),(c),false)
#endif
#endif
#ifndef FDOT2
#define FDOT2(a,b,c) fmaf((float)(a)[1],(float)(b)[1], fmaf((float)(a)[0],(float)(b)[0],(c)))
#endif

// ---- workspace layout (float offsets) ----
#define OF_QVEC  320000ull     // q_state @ W_q  [400]
#define OF_WKQ   320448ull     // wkq [400][4]
#define OF_THETA 322048ull     // scores [B][4][512]
#define OF_MU    387584ull     // mu     [B][4][512]
#define OF_HP    453120ull     // hp [B][4][400]
#define OF_LEN   504320ull     // lengths (int) [32]
#define OF_XWF   504384ull     // xW forward  [B*S][800]
#define OF_XWB   13611584ull   // xW backward (natural s order) [B*S][800]
#define OF_HF    26718784ull   // h_f [B*S][200]
#define OF_HB    29995584ull   // h_b [B*S][200]

// -------- lengths from mask (dtype auto-detect: u8 / i32 / i64) --------
__global__ void k_lengths(const void* __restrict__ mask, int* __restrict__ lengths) {
  int b = blockIdx.x, lane = threadIdx.x;
  const unsigned char* mb = (const unsigned char*)mask;
  int mode;
  if (mb[1] != 0) mode = 0;
  else if (((const int*)mask)[1] != 0) mode = 1;
  else mode = 2;
  int cnt = 0;
  for (int s = lane; s < S_; s += 64) {
    int v;
    if (mode == 0)      v = mb[b*S_ + s] ? 1 : 0;
    else if (mode == 1) v = ((const int*)mask)[b*S_ + s] ? 1 : 0;
    else                v = ((const long long*)mask)[b*S_ + s] ? 1 : 0;
    cnt += v;
  }
  for (int off = 32; off; off >>= 1) cnt += __shfl_xor(cnt, off);
  if (lane == 0) lengths[b] = cnt;
}

// -------- qvec = q_state @ W_q --------
__global__ void k_qvec(const float* __restrict__ qs, const float* __restrict__ Wq,
                       float* __restrict__ qvec) {
  __shared__ float qsl[ENC_];
  int t = threadIdx.x;
  if (t < ENC_) qsl[t] = qs[t];
  __syncthreads();
  if (t < ENC_) {
    float acc = 0.f;
    for (int i = 0; i < ENC_; ++i) acc += qsl[i] * Wq[(size_t)i*ENC_ + t];
    qvec[t] = acc;
  }
}

// -------- wkq[e][head] --------
__global__ void k_wkq(const float* __restrict__ Wk, const float* __restrict__ qvec,
                      float* __restrict__ wkq) {
  int t = threadIdx.x;
  int e = blockIdx.x*64 + (t >> 2);
  int head = t & 3;
  if (e < ENC_) {
    float acc = 0.f;
    const float* row = Wk + (size_t)e*ENC_ + head*100;
    const float* qv  = qvec + head*100;
    for (int d = 0; d < 100; ++d) acc += row[d]*qv[d];
    wkq[e*4 + head] = acc;
  }
}

// -------- input projections via fp16 MFMA (unchanged) --------
__global__ __launch_bounds__(256) void k_gemm_mfma(
    const int* __restrict__ x, const float* __restrict__ emb,
    const float* __restrict__ wf, const float* __restrict__ wb,
    const float* __restrict__ bf, const float* __restrict__ bb,
    float* __restrict__ xWf, float* __restrict__ xWb)
{
  __shared__ int xid[128];
  __shared__ __align__(16) _Float16 sA[128][40];
  __shared__ __align__(16) _Float16 sB[64][40];
  const int t = threadIdx.x;
  const int row0 = blockIdx.x * 128;
  const int col0 = blockIdx.y * 64;
  if (t < 128) xid[t] = x[row0 + t];
  const int w = t >> 6, lane = t & 63;
  const int wr = w >> 1, wc = w & 1;
  f32x4 acc[4][2] = {};
  const int ar = t >> 1, ah = t & 1;
  const int bc = t >> 2, bq = t & 3;
  const int colg = col0 + bc;
  const float* wsrc = (colg < 800) ? (wf + (size_t)colg*300)
                                   : (wb + (size_t)(colg-800)*300);
  __syncthreads();
  const float* asrc = emb + (size_t)xid[ar]*300;
  for (int kc = 0; kc < 10; ++kc) {
    const int k0 = kc*32;
    {
      const int kb = k0 + ah*16;
      _Float16 tmp[16];
      if (kb + 15 < 300) {
        #pragma unroll
        for (int q = 0; q < 4; ++q) {
          float4 a = *(const float4*)(asrc + kb + 4*q);
          tmp[4*q]  =(_Float16)a.x; tmp[4*q+1]=(_Float16)a.y;
          tmp[4*q+2]=(_Float16)a.z; tmp[4*q+3]=(_Float16)a.w;
        }
      } else {
        #pragma unroll
        for (int i = 0; i < 16; ++i)
          tmp[i] = (_Float16)((kb+i < 300) ? asrc[kb+i] : 0.f);
      }
      *(f16x8*)&sA[ar][ah*16]   = *(f16x8*)&tmp[0];
      *(f16x8*)&sA[ar][ah*16+8] = *(f16x8*)&tmp[8];
    }
    {
      const int kb = k0 + bq*8;
      _Float16 tmp[8];
      if (kb + 7 < 300) {
        #pragma unroll
        for (int q = 0; q < 2; ++q) {
          float4 a = *(const float4*)(wsrc + kb + 4*q);
          tmp[4*q]  =(_Float16)a.x; tmp[4*q+1]=(_Float16)a.y;
          tmp[4*q+2]=(_Float16)a.z; tmp[4*q+3]=(_Float16)a.w;
        }
      } else {
        #pragma unroll
        for (int i = 0; i < 8; ++i)
          tmp[i] = (_Float16)((kb+i < 300) ? wsrc[kb+i] : 0.f);
      }
      *(f16x8*)&sB[bc][bq*8] = *(f16x8*)&tmp[0];
    }
    __syncthreads();
    const int fr = lane & 15, kg = lane >> 4;
    f16x8 b0 = *(const f16x8*)&sB[wc*32 + fr][kg*8];
    f16x8 b1 = *(const f16x8*)&sB[wc*32 + 16 + fr][kg*8];
    #pragma unroll
    for (int m = 0; m < 4; ++m) {
      f16x8 afrag = *(const f16x8*)&sA[wr*64 + m*16 + fr][kg*8];
      acc[m][0] = __builtin_amdgcn_mfma_f32_16x16x32_f16(afrag, b0, acc[m][0], 0,0,0);
      acc[m][1] = __builtin_amdgcn_mfma_f32_16x16x32_f16(afrag, b1, acc[m][1], 0,0,0);
    }
    __syncthreads();
  }
  const int crb = (lane >> 4) * 4, ccol = lane & 15;
  #pragma unroll
  for (int n = 0; n < 2; ++n) {
    int colg2 = col0 + wc*32 + n*16 + ccol;
    bool isF = colg2 < 800;
    int colo = isF ? colg2 : colg2 - 800;
    float bias = isF ? bf[colo] : bb[colo];
    float* dst = isF ? xWf : xWb;
    #pragma unroll
    for (int m = 0; m < 4; ++m) {
      int row = row0 + wr*64 + m*16 + crb;
      #pragma unroll
      for (int r = 0; r < 4; ++r)
        dst[(size_t)(row+r)*800 + colo] = acc[m][n][r] + bias;
    }
  }
}

// -------- LSTM v3: k-split lanes, in-wave gate reduce, 1 barrier/step --------
// 64 WGs (one per dir,b chain) x 832 thr (13 waves). Lane = (q,u):
// k-quarter q = lane>>4, unit u = 16*wave + (lane&15) (units 0..199 valid).
// Lane holds ALL 4 gate rows of its unit restricted to k in [50q,50q+50):
// 4 x 25 half2 = 100 VGPRs (loaded once). Per step:
//   read own h-quarter from LDS (6 uint4 + 1 uint, lane-distinct, conflict-
//   free: 7 insts/wave vs the old 26 broadcast b128) -> 100 fdot2 into 4
//   gate partials -> cross-q reduce via shfl_xor(16/32) -> every lane has
//   full (i,f,g,o) preacts -> in-lane elementwise (c redundant across q) ->
//   q==0 publishes h (fp16 -> LDS double buffer, fp32 -> global) -> ONE
//   barrier. No gact LDS, no serial 200-thread tail.
__global__
__attribute__((amdgpu_flat_work_group_size(832, 832), amdgpu_waves_per_eu(1, 4)))
void k_lstm_v3(
    const float* __restrict__ xWf, const float* __restrict__ xWb,
    const float* __restrict__ whhf, const float* __restrict__ whhb,
    const int* __restrict__ lengths,
    float* __restrict__ h_f, float* __restrict__ h_b)
{
  const int bid = blockIdx.x;
  const int dir = bid >> 5, b = bid & 31;
  const float* __restrict__ xW  = dir ? xWb : xWf;
  const float* __restrict__ whh = dir ? whhb : whhf;
  float* __restrict__ hout      = dir ? h_b : h_f;
  const int len = lengths[b];
  const int t = threadIdx.x;
  const int wave = t >> 6, lane = t & 63;
  const int q = lane >> 4, u16 = lane & 15;
  const int unit = wave*16 + u16;              // 0..207
  const bool valid = (unit < H_);
  const int uc = valid ? unit : (H_-1);        // clamped for safe addressing

  // h double buffer as fp16, quarter-padded: [buf][quarter][64 fp16]
  __shared__ __align__(16) _Float16 hxh[2][4][64];

  // ---- one-time weight preload: w[g][j] = whh[g*200+unit][50q+2j .. +1] ----
  half2v w0[25], w1[25], w2[25], w3[25];
  {
    const float* r0 = whh + ((size_t)(0*H_ + uc))*H_ + 50*q;
    const float* r1 = whh + ((size_t)(1*H_ + uc))*H_ + 50*q;
    const float* r2 = whh + ((size_t)(2*H_ + uc))*H_ + 50*q;
    const float* r3 = whh + ((size_t)(3*H_ + uc))*H_ + 50*q;
    #pragma unroll
    for (int j = 0; j < 25; ++j) {
      float2 a0 = *(const float2*)(r0 + 2*j);
      float2 a1 = *(const float2*)(r1 + 2*j);
      float2 a2 = *(const float2*)(r2 + 2*j);
      float2 a3 = *(const float2*)(r3 + 2*j);
      w0[j] = half2v{(_Float16)a0.x, (_Float16)a0.y};
      w1[j] = half2v{(_Float16)a1.x, (_Float16)a1.y};
      w2[j] = half2v{(_Float16)a2.x, (_Float16)a2.y};
      w3[j] = half2v{(_Float16)a3.x, (_Float16)a3.y};
    }
  }

  // zero h buffer 0 (512 fp16 over both buffers is 1KB; only buf0 is read at step 0)
  if (t < 128) ((unsigned int*)&hxh[0][0][0])[t] = 0u;
  float cst = 0.f;
  const float* xbase = xW + (size_t)b*S_*G4_;
  __syncthreads();

  for (int step = 0; step < len; ++step) {
    const int pos = dir ? (len-1-step) : step;
    const int p = step & 1;
    // xW gate inputs for this unit (4 loads; q-redundant, L1-broadcast)
    const float* xr = xbase + (size_t)pos*G4_ + uc;
    float xi = xr[0], xf = xr[H_], xg = xr[2*H_], xo = xr[3*H_];
    // read own h-quarter: 24 words as 6 uint4 + 1 tail word
    const unsigned int* hq = (const unsigned int*)&hxh[p][q][0];
    float a0 = 0.f, a1 = 0.f, a2 = 0.f, a3 = 0.f;
    #pragma unroll
    for (int jj = 0; jj < 6; ++jj) {
      uint4 hw4 = *(const uint4*)&hq[4*jj];
      #pragma unroll
      for (int e = 0; e < 4; ++e) {
        unsigned int wv = (e==0)?hw4.x:(e==1)?hw4.y:(e==2)?hw4.z:hw4.w;
        half2v hh = __builtin_bit_cast(half2v, wv);
        const int j = 4*jj + e;
        a0 = FDOT2(w0[j], hh, a0);
        a1 = FDOT2(w1[j], hh, a1);
        a2 = FDOT2(w2[j], hh, a2);
        a3 = FDOT2(w3[j], hh, a3);
      }
    }
    {
      half2v hh = __builtin_bit_cast(half2v, hq[24]);
      a0 = FDOT2(w0[24], hh, a0);
      a1 = FDOT2(w1[24], hh, a1);
      a2 = FDOT2(w2[24], hh, a2);
      a3 = FDOT2(w3[24], hh, a3);
    }
    // cross-q reduce (lanes {q*16+u} share a unit)
    a0 += __shfl_xor(a0, 16); a0 += __shfl_xor(a0, 32);
    a1 += __shfl_xor(a1, 16); a1 += __shfl_xor(a1, 32);
    a2 += __shfl_xor(a2, 16); a2 += __shfl_xor(a2, 32);
    a3 += __shfl_xor(a3, 16); a3 += __shfl_xor(a3, 32);
    // gates + elementwise (redundant across the 4 q-lanes; bitwise identical)
    float gi = a0 + xi, gf = a1 + xf, gg = a2 + xg, go = a3 + xo;
    float ig = 1.f/(1.f+__expf(-gi));
    float fg = 1.f/(1.f+__expf(-gf));
    float og = 1.f/(1.f+__expf(-go));
    float ggc = fminf(fmaxf(gg, -10.f), 10.f);
    float eg = __expf(2.f*ggc);
    cst = fg*cst + ig*((eg-1.f)/(eg+1.f));
    float cc = fminf(fmaxf(cst, -10.f), 10.f);
    float ec = __expf(2.f*cc);
    float hn = og*((ec-1.f)/(ec+1.f));
    // publish (one lane per unit)
    if (valid && q == 0) {
      hout[((size_t)b*S_ + pos)*H_ + unit] = hn;
      hxh[p^1][unit/50][unit%50] = (_Float16)hn;
    }
    __syncthreads();
  }
}

// -------- scores --------
__global__ __launch_bounds__(256) void k_scores(
    const float* __restrict__ hf, const float* __restrict__ hb,
    const float* __restrict__ wkq, const int* __restrict__ lengths,
    float* __restrict__ theta)
{
  int wid = blockIdx.x*4 + (threadIdx.x >> 6);
  int lane = threadIdx.x & 63;
  int b = wid >> 9, s = wid & 511;
  const float* hfr = hf + ((size_t)b*S_ + s)*H_;
  const float* hbr = hb + ((size_t)b*S_ + s)*H_;
  bool valid = s < lengths[b];
  float a0=0.f, a1=0.f, a2=0.f, a3=0.f;
  if (valid) {
    for (int e = lane; e < ENC_; e += 64) {
      float hv = (e < H_) ? hfr[e] : hbr[e-H_];
      float4 w = *(const float4*)(wkq + e*4);
      a0 += hv*w.x; a1 += hv*w.y; a2 += hv*w.z; a3 += hv*w.w;
    }
    for (int off = 32; off; off >>= 1) {
      a0 += __shfl_xor(a0, off); a1 += __shfl_xor(a1, off);
      a2 += __shfl_xor(a2, off); a3 += __shfl_xor(a3, off);
    }
  }
  if (lane == 0) {
    size_t base = (size_t)b*2048 + s;
    theta[base       ] = valid ? SCALE_*a0 : NEGV;
    theta[base +  512] = valid ? SCALE_*a1 : NEGV;
    theta[base + 1024] = valid ? SCALE_*a2 : NEGV;
    theta[base + 1536] = valid ? SCALE_*a3 : NEGV;
  }
}

// -------- sparseMAP budget projection --------
__global__ void k_sparsemap(const float* __restrict__ theta, const int* __restrict__ lengths,
                            float* __restrict__ mu) {
  int pid = blockIdx.x;
  int lane = threadIdx.x;
  const float* th = theta + (size_t)pid*512;
  float v[8];
  #pragma unroll
  for (int i = 0; i < 8; ++i) v[i] = th[i*64 + lane];
  float kf = rintf(0.2f * (float)lengths[pid >> 2]);
  float mn = v[0], mx = v[0];
  #pragma unroll
  for (int i = 1; i < 8; ++i) { mn = fminf(mn, v[i]); mx = fmaxf(mx, v[i]); }
  for (int off = 32; off; off >>= 1) {
    mn = fminf(mn, __shfl_xor(mn, off)); mx = fmaxf(mx, __shfl_xor(mx, off));
  }
  float lo = mn - 1.f, hi = mx;
  for (int it = 0; it < 60; ++it) {
    float mid = 0.5f*(lo + hi);
    float s = 0.f;
    #pragma unroll
    for (int i = 0; i < 8; ++i) s += fminf(fmaxf(v[i]-mid, 0.f), 1.f);
    for (int off = 32; off; off >>= 1) s += __shfl_xor(s, off);
    bool big = s > kf;
    lo = big ? mid : lo;
    hi = big ? hi : mid;
  }
  float tau0 = 0.5f*(lo + hi);
  float fs = 0.f, nU = 0.f, nS = 0.f;
  #pragma unroll
  for (int i = 0; i < 8; ++i) {
    float m0 = v[i] - tau0;
    if (m0 >= 1.f) nU += 1.f;
    else if (m0 > 0.f) { fs += v[i]; nS += 1.f; }
  }
  for (int off = 32; off; off >>= 1) {
    fs += __shfl_xor(fs, off); nU += __shfl_xor(nU, off); nS += __shfl_xor(nS, off);
  }
  float tau = (fs + nU - kf) / fmaxf(nS, 1.f);
  tau = (nS > 0.f) ? tau : tau0;
  float* mo = mu + (size_t)pid*512;
  #pragma unroll
  for (int i = 0; i < 8; ++i) mo[i*64 + lane] = fminf(fmaxf(v[i]-tau, 0.f), 1.f);
}

// -------- hp[b,head,e] = sum_s mu * h --------
__global__ __launch_bounds__(512) void k_hp(
    const float* __restrict__ mu, const float* __restrict__ hf,
    const float* __restrict__ hb, float* __restrict__ hp)
{
  __shared__ float mul[512];
  int pid = blockIdx.x, b = pid >> 2;
  int t = threadIdx.x;
  mul[t] = mu[(size_t)pid*512 + t];
  __syncthreads();
  if (t < ENC_) {
    const float* hsrc = (t < H_) ? (hf + t) : (hb + (t - H_));
    float acc = 0.f;
    for (int s = 0; s < 512; ++s) {
      float m = mul[s];
      if (m != 0.f) acc += m * hsrc[((size_t)b*S_ + s)*H_];
    }
    hp[(size_t)pid*ENC_ + t] = acc;
  }
}

// -------- head --------
__global__ __launch_bounds__(512) void k_head(
    const float* __restrict__ hp, const float* __restrict__ Wv,
    const float* __restrict__ Wout, const float* __restrict__ Wh,
    const float* __restrict__ bh, float* __restrict__ out)
{
  __shared__ float hpl[1600];
  __shared__ float ppl[ENC_];
  __shared__ float ojl[ENC_];
  __shared__ float red[512];
  int b = blockIdx.x, t = threadIdx.x;
  for (int i = t; i < 1600; i += 512) hpl[i] = hp[(size_t)b*1600 + i];
  __syncthreads();
  if (t < ENC_) {
    int head = t / 100;
    float acc = 0.f;
    for (int e = 0; e < ENC_; ++e) acc += hpl[head*ENC_ + e] * Wv[(size_t)e*ENC_ + t];
    ppl[t] = acc;
  }
  __syncthreads();
  if (t < ENC_) {
    float acc = 0.f;
    for (int c = 0; c < ENC_; ++c) acc += ppl[c] * Wout[(size_t)c*ENC_ + t];
    ojl[t] = acc;
  }
  __syncthreads();
  red[t] = (t < ENC_) ? ojl[t]*Wh[t] : 0.f;
  __syncthreads();
  for (int sft = 256; sft; sft >>= 1) {
    if (t < sft) red[t] += red[t+sft];
    __syncthreads();
  }
  if (t == 0) out[b] = 1.f/(1.f + expf(-(red[0] + bh[0])));
}

// -------- z --------
__global__ void k_z(const float* __restrict__ mu, const int* __restrict__ lengths,
                    float* __restrict__ out) {
  int idx = blockIdx.x*256 + threadIdx.x;
  int b = idx >> 9, s = idx & 511;
  float zz = 0.f;
  if (s < lengths[b]) {
    size_t base = (size_t)b*2048 + s;
    zz = 0.25f*(mu[base] + mu[base+512] + mu[base+1024] + mu[base+1536]);
  }
  out[32 + idx] = zz;
}

extern "C" void kernel_launch(void* const* d_in, const int* in_sizes, int n_in,
                              void* d_out, int out_size, void* d_ws, size_t ws_size,
                              hipStream_t stream) {
  const int*   x    = (const int*)d_in[0];
  const void*  mask = d_in[1];
  const float* emb  = (const float*)d_in[2];
  const float* wihf = (const float*)d_in[3];
  const float* whhf = (const float*)d_in[4];
  const float* bf   = (const float*)d_in[5];
  const float* wihb = (const float*)d_in[6];
  const float* whhb = (const float*)d_in[7];
  const float* bb   = (const float*)d_in[8];
  const float* qs   = (const float*)d_in[9];
  const float* Wq   = (const float*)d_in[10];
  const float* Wk   = (const float*)d_in[11];
  const float* Wv   = (const float*)d_in[12];
  const float* Wout = (const float*)d_in[13];
  const float* Wh   = (const float*)d_in[14];
  const float* bh   = (const float*)d_in[15];
  float* out = (float*)d_out;
  float* W = (float*)d_ws;
  int* lengths = (int*)(W + OF_LEN);

  k_lengths<<<32, 64, 0, stream>>>(mask, lengths);
  k_qvec<<<1, 512, 0, stream>>>(qs, Wq, W+OF_QVEC);
  k_wkq<<<7, 256, 0, stream>>>(Wk, W+OF_QVEC, W+OF_WKQ);
  k_gemm_mfma<<<dim3(128, 25), 256, 0, stream>>>(x, emb, wihf, wihb, bf, bb,
                                                 W+OF_XWF, W+OF_XWB);
  k_lstm_v3<<<64, 832, 0, stream>>>(W+OF_XWF, W+OF_XWB, whhf, whhb,
                                    lengths, W+OF_HF, W+OF_HB);
  k_scores<<<4096, 256, 0, stream>>>(W+OF_HF, W+OF_HB, W+OF_WKQ, lengths, W+OF_THETA);
  k_sparsemap<<<128, 64, 0, stream>>>(W+OF_THETA, lengths, W+OF_MU);
  k_hp<<<128, 512, 0, stream>>>(W+OF_MU, W+OF_HF, W+OF_HB, W+OF_HP);
  k_head<<<32, 512, 0, stream>>>(W+OF_HP, Wv, Wout, Wh, bh, out);
  k_z<<<64, 256, 0, stream>>>(W+OF_MU, lengths, out);
}

// Round 8
// 877.390 us; speedup vs baseline: 1.2790x; 1.2790x over previous
//
#include <hip/hip_runtime.h>
#include <hip/hip_bf16.h>
#include <math.h>

// Problem constants
#define B_   32
#define S_   512
#define V_   30000
#define E_   300
#define H_   200
#define NH_  4
#define ENC_ 400
#define G4_  800     // 4*H
#define NEGV  (-1e9f)
#define SCALE_ 1000.0f

typedef _Float16 half2v __attribute__((ext_vector_type(2)));
typedef _Float16 f16x8  __attribute__((ext_vector_type(8)));
typedef float    f32x4  __attribute__((ext_vector_type(4)));

#if defined(__has_builtin)
#if __has_builtin(__builtin_amdgcn_fdot2)
#define FDOT2(a,b,c) __builtin_amdgcn_fdot2((a),(b),(c),false)
#endif
#endif
#ifndef FDOT2
#define FDOT2(a,b,c) fmaf((float)(a)[1],(float)(b)[1], fmaf((float)(a)[0],(float)(b)[0],(c)))
#endif

// ---- workspace layout (float offsets) ----
#define OF_QVEC  320000ull     // q_state @ W_q  [400]
#define OF_WKQ   320448ull     // wkq [400][4]
#define OF_THETA 322048ull     // scores [B][4][512]
#define OF_MU    387584ull     // mu     [B][4][512]
#define OF_HP    453120ull     // hp [B][4][400]
#define OF_LEN   504320ull     // lengths (int) [32]
#define OF_XWF   504384ull     // xW forward  [B*S][800]
#define OF_XWB   13611584ull   // xW backward (natural s order) [B*S][800]
#define OF_HF    26718784ull   // h_f [B*S][200]
#define OF_HB    29995584ull   // h_b [B*S][200]

// -------- lengths from mask (dtype auto-detect: u8 / i32 / i64) --------
__global__ void k_lengths(const void* __restrict__ mask, int* __restrict__ lengths) {
  int b = blockIdx.x, lane = threadIdx.x;
  const unsigned char* mb = (const unsigned char*)mask;
  int mode;
  if (mb[1] != 0) mode = 0;
  else if (((const int*)mask)[1] != 0) mode = 1;
  else mode = 2;
  int cnt = 0;
  for (int s = lane; s < S_; s += 64) {
    int v;
    if (mode == 0)      v = mb[b*S_ + s] ? 1 : 0;
    else if (mode == 1) v = ((const int*)mask)[b*S_ + s] ? 1 : 0;
    else                v = ((const long long*)mask)[b*S_ + s] ? 1 : 0;
    cnt += v;
  }
  for (int off = 32; off; off >>= 1) cnt += __shfl_xor(cnt, off);
  if (lane == 0) lengths[b] = cnt;
}

// -------- qvec = q_state @ W_q --------
__global__ void k_qvec(const float* __restrict__ qs, const float* __restrict__ Wq,
                       float* __restrict__ qvec) {
  __shared__ float qsl[ENC_];
  int t = threadIdx.x;
  if (t < ENC_) qsl[t] = qs[t];
  __syncthreads();
  if (t < ENC_) {
    float acc = 0.f;
    for (int i = 0; i < ENC_; ++i) acc += qsl[i] * Wq[(size_t)i*ENC_ + t];
    qvec[t] = acc;
  }
}

// -------- wkq[e][head] --------
__global__ void k_wkq(const float* __restrict__ Wk, const float* __restrict__ qvec,
                      float* __restrict__ wkq) {
  int t = threadIdx.x;
  int e = blockIdx.x*64 + (t >> 2);
  int head = t & 3;
  if (e < ENC_) {
    float acc = 0.f;
    const float* row = Wk + (size_t)e*ENC_ + head*100;
    const float* qv  = qvec + head*100;
    for (int d = 0; d < 100; ++d) acc += row[d]*qv[d];
    wkq[e*4 + head] = acc;
  }
}

// -------- input projections via fp16 MFMA (unchanged) --------
__global__ __launch_bounds__(256) void k_gemm_mfma(
    const int* __restrict__ x, const float* __restrict__ emb,
    const float* __restrict__ wf, const float* __restrict__ wb,
    const float* __restrict__ bf, const float* __restrict__ bb,
    float* __restrict__ xWf, float* __restrict__ xWb)
{
  __shared__ int xid[128];
  __shared__ __align__(16) _Float16 sA[128][40];
  __shared__ __align__(16) _Float16 sB[64][40];
  const int t = threadIdx.x;
  const int row0 = blockIdx.x * 128;
  const int col0 = blockIdx.y * 64;
  if (t < 128) xid[t] = x[row0 + t];
  const int w = t >> 6, lane = t & 63;
  const int wr = w >> 1, wc = w & 1;
  f32x4 acc[4][2] = {};
  const int ar = t >> 1, ah = t & 1;
  const int bc = t >> 2, bq = t & 3;
  const int colg = col0 + bc;
  const float* wsrc = (colg < 800) ? (wf + (size_t)colg*300)
                                   : (wb + (size_t)(colg-800)*300);
  __syncthreads();
  const float* asrc = emb + (size_t)xid[ar]*300;
  for (int kc = 0; kc < 10; ++kc) {
    const int k0 = kc*32;
    {
      const int kb = k0 + ah*16;
      _Float16 tmp[16];
      if (kb + 15 < 300) {
        #pragma unroll
        for (int q = 0; q < 4; ++q) {
          float4 a = *(const float4*)(asrc + kb + 4*q);
          tmp[4*q]  =(_Float16)a.x; tmp[4*q+1]=(_Float16)a.y;
          tmp[4*q+2]=(_Float16)a.z; tmp[4*q+3]=(_Float16)a.w;
        }
      } else {
        #pragma unroll
        for (int i = 0; i < 16; ++i)
          tmp[i] = (_Float16)((kb+i < 300) ? asrc[kb+i] : 0.f);
      }
      *(f16x8*)&sA[ar][ah*16]   = *(f16x8*)&tmp[0];
      *(f16x8*)&sA[ar][ah*16+8] = *(f16x8*)&tmp[8];
    }
    {
      const int kb = k0 + bq*8;
      _Float16 tmp[8];
      if (kb + 7 < 300) {
        #pragma unroll
        for (int q = 0; q < 2; ++q) {
          float4 a = *(const float4*)(wsrc + kb + 4*q);
          tmp[4*q]  =(_Float16)a.x; tmp[4*q+1]=(_Float16)a.y;
          tmp[4*q+2]=(_Float16)a.z; tmp[4*q+3]=(_Float16)a.w;
        }
      } else {
        #pragma unroll
        for (int i = 0; i < 8; ++i)
          tmp[i] = (_Float16)((kb+i < 300) ? wsrc[kb+i] : 0.f);
      }
      *(f16x8*)&sB[bc][bq*8] = *(f16x8*)&tmp[0];
    }
    __syncthreads();
    const int fr = lane & 15, kg = lane >> 4;
    f16x8 b0 = *(const f16x8*)&sB[wc*32 + fr][kg*8];
    f16x8 b1 = *(const f16x8*)&sB[wc*32 + 16 + fr][kg*8];
    #pragma unroll
    for (int m = 0; m < 4; ++m) {
      f16x8 afrag = *(const f16x8*)&sA[wr*64 + m*16 + fr][kg*8];
      acc[m][0] = __builtin_amdgcn_mfma_f32_16x16x32_f16(afrag, b0, acc[m][0], 0,0,0);
      acc[m][1] = __builtin_amdgcn_mfma_f32_16x16x32_f16(afrag, b1, acc[m][1], 0,0,0);
    }
    __syncthreads();
  }
  const int crb = (lane >> 4) * 4, ccol = lane & 15;
  #pragma unroll
  for (int n = 0; n < 2; ++n) {
    int colg2 = col0 + wc*32 + n*16 + ccol;
    bool isF = colg2 < 800;
    int colo = isF ? colg2 : colg2 - 800;
    float bias = isF ? bf[colo] : bb[colo];
    float* dst = isF ? xWf : xWb;
    #pragma unroll
    for (int m = 0; m < 4; ++m) {
      int row = row0 + wr*64 + m*16 + crb;
      #pragma unroll
      for (int r = 0; r < 4; ++r)
        dst[(size_t)(row+r)*800 + colo] = acc[m][n][r] + bias;
    }
  }
}

// -------- fp16 weight-stationary LSTM body (shared by both variants) --------
// 64 WGs (one per dir,b chain) x 1024 thr. Thread t<800 holds W_hh row t as
// 100 packed half2 VGPRs: w[m]=W[t][2m..2m+1]. Per step: coalesced xv load ->
// 100 fdot2 vs fp16 h broadcast from LDS -> own-gate nonlinearity -> gact[t]
// -> barrier -> t<200: c/h update, publish h (global fp32 + LDS fp16) ->
// barrier.
__device__ __forceinline__ void lstm_v2_body(
    const float* __restrict__ xWf, const float* __restrict__ xWb,
    const float* __restrict__ whhf, const float* __restrict__ whhb,
    const int* __restrict__ lengths,
    float* __restrict__ h_f, float* __restrict__ h_b)
{
  const int bid = blockIdx.x;
  const int dir = bid >> 5, b = bid & 31;
  const float* __restrict__ xW  = dir ? xWb : xWf;
  const float* __restrict__ whh = dir ? whhb : whhf;
  float* __restrict__ hout      = dir ? h_b : h_f;
  const int len = lengths[b];
  const int t = threadIdx.x;
  const int active = (t < G4_);

  __shared__ __align__(16) _Float16 hbh[200];
  __shared__ float gact[G4_];

  // one-time weight preload: w[m] = row t, k = 2m..2m+1 (m = 0..99)
  half2v w[100];
  if (active) {
    const float* rp = whh + (size_t)t*H_;
    #pragma unroll
    for (int j = 0; j < 50; ++j) {
      float2 a = *(const float2*)(rp + 2*j);
      w[j] = half2v{(_Float16)a.x, (_Float16)a.y};
    }
    #pragma unroll
    for (int j = 0; j < 50; ++j) {
      float2 a = *(const float2*)(rp + 100 + 2*j);
      w[50+j] = half2v{(_Float16)a.x, (_Float16)a.y};
    }
  }
  if (t < 200) hbh[t] = (_Float16)0.f;
  float cst = 0.f;
  const float* xbase = xW + (size_t)b*S_*G4_;
  const int isTanh = (t >= 400) && (t < 600);
  __syncthreads();

  for (int step = 0; step < len; ++step) {
    const int pos = dir ? (len-1-step) : step;
    if (active) {
      float xv = xbase[(size_t)pos*G4_ + t];     // coalesced; hides under dot
      float a0 = 0.f, a1 = 0.f;
      #pragma unroll
      for (int j = 0; j < 12; ++j) {             // k = 0..95
        float4 h4 = *(const float4*)&hbh[8*j];
        a0 = FDOT2(w[4*j],   __builtin_bit_cast(half2v, h4.x), a0);
        a1 = FDOT2(w[4*j+1], __builtin_bit_cast(half2v, h4.y), a1);
        a0 = FDOT2(w[4*j+2], __builtin_bit_cast(half2v, h4.z), a0);
        a1 = FDOT2(w[4*j+3], __builtin_bit_cast(half2v, h4.w), a1);
      }
      { // k = 96..99
        float2 h2 = *(const float2*)&hbh[96];
        a0 = FDOT2(w[48], __builtin_bit_cast(half2v, h2.x), a0);
        a1 = FDOT2(w[49], __builtin_bit_cast(half2v, h2.y), a1);
      }
      #pragma unroll
      for (int j = 0; j < 12; ++j) {             // k = 100..195
        float4 h4 = *(const float4*)&hbh[100 + 8*j];
        a0 = FDOT2(w[50+4*j],   __builtin_bit_cast(half2v, h4.x), a0);
        a1 = FDOT2(w[50+4*j+1], __builtin_bit_cast(half2v, h4.y), a1);
        a0 = FDOT2(w[50+4*j+2], __builtin_bit_cast(half2v, h4.z), a0);
        a1 = FDOT2(w[50+4*j+3], __builtin_bit_cast(half2v, h4.w), a1);
      }
      { // k = 196..199
        float2 h2 = *(const float2*)&hbh[196];
        a0 = FDOT2(w[98], __builtin_bit_cast(half2v, h2.x), a0);
        a1 = FDOT2(w[99], __builtin_bit_cast(half2v, h2.y), a1);
      }
      float pre = a0 + a1 + xv;
      float act;
      if (isTanh) {
        float gc = fminf(fmaxf(pre, -10.f), 10.f);
        float e2 = __expf(2.f*gc);
        act = (e2-1.f)/(e2+1.f);
      } else {
        act = 1.f/(1.f+__expf(-pre));
      }
      gact[t] = act;
    }
    __syncthreads();
    if (t < 200) {
      float ig = gact[t], fg = gact[200+t], gg = gact[400+t], og = gact[600+t];
      cst = fg*cst + ig*gg;
      float cc = fminf(fmaxf(cst, -10.f), 10.f);
      float ec = __expf(2.f*cc);
      float hn = og*((ec-1.f)/(ec+1.f));
      hout[((size_t)b*S_ + pos)*H_ + t] = hn;
      hbh[t] = (_Float16)hn;
    }
    __syncthreads();
  }
}

// Fallback variant: allocator default (observed: 64 VGPRs, ~56 regs spilled,
// ~2900 cyc/step -> 678 us). Known-good baseline.
__global__ __launch_bounds__(1024) void k_lstm_v2(
    const float* __restrict__ xWf, const float* __restrict__ xWb,
    const float* __restrict__ whhf, const float* __restrict__ whhb,
    const int* __restrict__ lengths,
    float* __restrict__ h_f, float* __restrict__ h_b)
{
  lstm_v2_body(xWf, xWb, whhf, whhb, lengths, h_f, h_b);
}

// Big-register variant: amdgpu_num_vgpr(128) directly requests a 128-VGPR
// allocation (16 waves x 128 = 512 regs/SIMD = exactly the file; 1 WG/CU).
// If honored, the 100 weight half2s become truly register-resident (no
// spill). Host dispatch checks numRegs at runtime and only launches this
// variant if the allocation was actually granted.
__global__
__attribute__((amdgpu_flat_work_group_size(1024, 1024), amdgpu_num_vgpr(128)))
void k_lstm_v2_big(
    const float* __restrict__ xWf, const float* __restrict__ xWb,
    const float* __restrict__ whhf, const float* __restrict__ whhb,
    const int* __restrict__ lengths,
    float* __restrict__ h_f, float* __restrict__ h_b)
{
  lstm_v2_body(xWf, xWb, whhf, whhb, lengths, h_f, h_b);
}

// -------- scores --------
__global__ __launch_bounds__(256) void k_scores(
    const float* __restrict__ hf, const float* __restrict__ hb,
    const float* __restrict__ wkq, const int* __restrict__ lengths,
    float* __restrict__ theta)
{
  int wid = blockIdx.x*4 + (threadIdx.x >> 6);
  int lane = threadIdx.x & 63;
  int b = wid >> 9, s = wid & 511;
  const float* hfr = hf + ((size_t)b*S_ + s)*H_;
  const float* hbr = hb + ((size_t)b*S_ + s)*H_;
  bool valid = s < lengths[b];
  float a0=0.f, a1=0.f, a2=0.f, a3=0.f;
  if (valid) {
    for (int e = lane; e < ENC_; e += 64) {
      float hv = (e < H_) ? hfr[e] : hbr[e-H_];
      float4 w = *(const float4*)(wkq + e*4);
      a0 += hv*w.x; a1 += hv*w.y; a2 += hv*w.z; a3 += hv*w.w;
    }
    for (int off = 32; off; off >>= 1) {
      a0 += __shfl_xor(a0, off); a1 += __shfl_xor(a1, off);
      a2 += __shfl_xor(a2, off); a3 += __shfl_xor(a3, off);
    }
  }
  if (lane == 0) {
    size_t base = (size_t)b*2048 + s;
    theta[base       ] = valid ? SCALE_*a0 : NEGV;
    theta[base +  512] = valid ? SCALE_*a1 : NEGV;
    theta[base + 1024] = valid ? SCALE_*a2 : NEGV;
    theta[base + 1536] = valid ? SCALE_*a3 : NEGV;
  }
}

// -------- sparseMAP budget projection --------
__global__ void k_sparsemap(const float* __restrict__ theta, const int* __restrict__ lengths,
                            float* __restrict__ mu) {
  int pid = blockIdx.x;
  int lane = threadIdx.x;
  const float* th = theta + (size_t)pid*512;
  float v[8];
  #pragma unroll
  for (int i = 0; i < 8; ++i) v[i] = th[i*64 + lane];
  float kf = rintf(0.2f * (float)lengths[pid >> 2]);
  float mn = v[0], mx = v[0];
  #pragma unroll
  for (int i = 1; i < 8; ++i) { mn = fminf(mn, v[i]); mx = fmaxf(mx, v[i]); }
  for (int off = 32; off; off >>= 1) {
    mn = fminf(mn, __shfl_xor(mn, off)); mx = fmaxf(mx, __shfl_xor(mx, off));
  }
  float lo = mn - 1.f, hi = mx;
  for (int it = 0; it < 60; ++it) {
    float mid = 0.5f*(lo + hi);
    float s = 0.f;
    #pragma unroll
    for (int i = 0; i < 8; ++i) s += fminf(fmaxf(v[i]-mid, 0.f), 1.f);
    for (int off = 32; off; off >>= 1) s += __shfl_xor(s, off);
    bool big = s > kf;
    lo = big ? mid : lo;
    hi = big ? hi : mid;
  }
  float tau0 = 0.5f*(lo + hi);
  float fs = 0.f, nU = 0.f, nS = 0.f;
  #pragma unroll
  for (int i = 0; i < 8; ++i) {
    float m0 = v[i] - tau0;
    if (m0 >= 1.f) nU += 1.f;
    else if (m0 > 0.f) { fs += v[i]; nS += 1.f; }
  }
  for (int off = 32; off; off >>= 1) {
    fs += __shfl_xor(fs, off); nU += __shfl_xor(nU, off); nS += __shfl_xor(nS, off);
  }
  float tau = (fs + nU - kf) / fmaxf(nS, 1.f);
  tau = (nS > 0.f) ? tau : tau0;
  float* mo = mu + (size_t)pid*512;
  #pragma unroll
  for (int i = 0; i < 8; ++i) mo[i*64 + lane] = fminf(fmaxf(v[i]-tau, 0.f), 1.f);
}

// -------- hp[b,head,e] = sum_s mu * h --------
__global__ __launch_bounds__(512) void k_hp(
    const float* __restrict__ mu, const float* __restrict__ hf,
    const float* __restrict__ hb, float* __restrict__ hp)
{
  __shared__ float mul[512];
  int pid = blockIdx.x, b = pid >> 2;
  int t = threadIdx.x;
  mul[t] = mu[(size_t)pid*512 + t];
  __syncthreads();
  if (t < ENC_) {
    const float* hsrc = (t < H_) ? (hf + t) : (hb + (t - H_));
    float acc = 0.f;
    for (int s = 0; s < 512; ++s) {
      float m = mul[s];
      if (m != 0.f) acc += m * hsrc[((size_t)b*S_ + s)*H_];
    }
    hp[(size_t)pid*ENC_ + t] = acc;
  }
}

// -------- head --------
__global__ __launch_bounds__(512) void k_head(
    const float* __restrict__ hp, const float* __restrict__ Wv,
    const float* __restrict__ Wout, const float* __restrict__ Wh,
    const float* __restrict__ bh, float* __restrict__ out)
{
  __shared__ float hpl[1600];
  __shared__ float ppl[ENC_];
  __shared__ float ojl[ENC_];
  __shared__ float red[512];
  int b = blockIdx.x, t = threadIdx.x;
  for (int i = t; i < 1600; i += 512) hpl[i] = hp[(size_t)b*1600 + i];
  __syncthreads();
  if (t < ENC_) {
    int head = t / 100;
    float acc = 0.f;
    for (int e = 0; e < ENC_; ++e) acc += hpl[head*ENC_ + e] * Wv[(size_t)e*ENC_ + t];
    ppl[t] = acc;
  }
  __syncthreads();
  if (t < ENC_) {
    float acc = 0.f;
    for (int c = 0; c < ENC_; ++c) acc += ppl[c] * Wout[(size_t)c*ENC_ + t];
    ojl[t] = acc;
  }
  __syncthreads();
  red[t] = (t < ENC_) ? ojl[t]*Wh[t] : 0.f;
  __syncthreads();
  for (int sft = 256; sft; sft >>= 1) {
    if (t < sft) red[t] += red[t+sft];
    __syncthreads();
  }
  if (t == 0) out[b] = 1.f/(1.f + expf(-(red[0] + bh[0])));
}

// -------- z --------
__global__ void k_z(const float* __restrict__ mu, const int* __restrict__ lengths,
                    float* __restrict__ out) {
  int idx = blockIdx.x*256 + threadIdx.x;
  int b = idx >> 9, s = idx & 511;
  float zz = 0.f;
  if (s < lengths[b]) {
    size_t base = (size_t)b*2048 + s;
    zz = 0.25f*(mu[base] + mu[base+512] + mu[base+1024] + mu[base+1536]);
  }
  out[32 + idx] = zz;
}

extern "C" void kernel_launch(void* const* d_in, const int* in_sizes, int n_in,
                              void* d_out, int out_size, void* d_ws, size_t ws_size,
                              hipStream_t stream) {
  const int*   x    = (const int*)d_in[0];
  const void*  mask = d_in[1];
  const float* emb  = (const float*)d_in[2];
  const float* wihf = (const float*)d_in[3];
  const float* whhf = (const float*)d_in[4];
  const float* bf   = (const float*)d_in[5];
  const float* wihb = (const float*)d_in[6];
  const float* whhb = (const float*)d_in[7];
  const float* bb   = (const float*)d_in[8];
  const float* qs   = (const float*)d_in[9];
  const float* Wq   = (const float*)d_in[10];
  const float* Wk   = (const float*)d_in[11];
  const float* Wv   = (const float*)d_in[12];
  const float* Wout = (const float*)d_in[13];
  const float* Wh   = (const float*)d_in[14];
  const float* bh   = (const float*)d_in[15];
  float* out = (float*)d_out;
  float* W = (float*)d_ws;
  int* lengths = (int*)(W + OF_LEN);

  // Runtime check: was the amdgpu_num_vgpr(128) allocation actually granted?
  // Pure host-side query, deterministic, graph-capture-safe.
  static int big_regs = -1;   // cached; deterministic across calls
  if (big_regs < 0) {
    hipFuncAttributes fa{};
    big_regs = (hipFuncGetAttributes(&fa, (const void*)k_lstm_v2_big) == hipSuccess)
             ? fa.numRegs : 0;
  }
  const bool use_big = (big_regs >= 100);

  k_lengths<<<32, 64, 0, stream>>>(mask, lengths);
  k_qvec<<<1, 512, 0, stream>>>(qs, Wq, W+OF_QVEC);
  k_wkq<<<7, 256, 0, stream>>>(Wk, W+OF_QVEC, W+OF_WKQ);
  k_gemm_mfma<<<dim3(128, 25), 256, 0, stream>>>(x, emb, wihf, wihb, bf, bb,
                                                 W+OF_XWF, W+OF_XWB);
  if (use_big)
    k_lstm_v2_big<<<64, 1024, 0, stream>>>(W+OF_XWF, W+OF_XWB, whhf, whhb,
                                           lengths, W+OF_HF, W+OF_HB);
  else
    k_lstm_v2<<<64, 1024, 0, stream>>>(W+OF_XWF, W+OF_XWB, whhf, whhb,
                                       lengths, W+OF_HF, W+OF_HB);
  k_scores<<<4096, 256, 0, stream>>>(W+OF_HF, W+OF_HB, W+OF_WKQ, lengths, W+OF_THETA);
  k_sparsemap<<<128, 64, 0, stream>>>(W+OF_THETA, lengths, W+OF_MU);
  k_hp<<<128, 512, 0, stream>>>(W+OF_MU, W+OF_HF, W+OF_HB, W+OF_HP);
  k_head<<<32, 512, 0, stream>>>(W+OF_HP, Wv, Wout, Wh, bh, out);
  k_z<<<64, 256, 0, stream>>>(W+OF_MU, lengths, out);
}

// Round 9
// 876.233 us; speedup vs baseline: 1.2807x; 1.0013x over previous
//
#include <hip/hip_runtime.h>
#include <hip/hip_bf16.h>
#include <math.h>

// Problem constants
#define B_   32
#define S_   512
#define V_   30000
#define E_   300
#define H_   200
#define NH_  4
#define ENC_ 400
#define G4_  800     // 4*H
#define NEGV  (-1e9f)
#define SCALE_ 1000.0f

typedef _Float16 half2v __attribute__((ext_vector_type(2)));
typedef _Float16 f16x8  __attribute__((ext_vector_type(8)));
typedef float    f32x4  __attribute__((ext_vector_type(4)));

#if defined(__has_builtin)
#if __has_builtin(__builtin_amdgcn_fdot2)
#define FDOT2(a,b,c) __builtin_amdgcn_fdot2((a),(b),(c),false)
#endif
#endif
#ifndef FDOT2
#define FDOT2(a,b,c) fmaf((float)(a)[1],(float)(b)[1], fmaf((float)(a)[0],(float)(b)[0],(c)))
#endif

// ---- workspace layout (float offsets) ----
#define OF_QVEC  320000ull     // q_state @ W_q  [400]
#define OF_WKQ   320448ull     // wkq [400][4]
#define OF_THETA 322048ull     // scores [B][4][512]
#define OF_MU    387584ull     // mu     [B][4][512]
#define OF_HP    453120ull     // hp [B][4][400]
#define OF_LEN   504320ull     // lengths (int) [32]
#define OF_XWF   504384ull     // xW forward  [B*S][800]
#define OF_XWB   13611584ull   // xW backward (natural s order) [B*S][800]
#define OF_HF    26718784ull   // h_f [B*S][200]
#define OF_HB    29995584ull   // h_b [B*S][200]

// -------- lengths from mask (dtype auto-detect: u8 / i32 / i64) --------
__global__ void k_lengths(const void* __restrict__ mask, int* __restrict__ lengths) {
  int b = blockIdx.x, lane = threadIdx.x;
  const unsigned char* mb = (const unsigned char*)mask;
  int mode;
  if (mb[1] != 0) mode = 0;
  else if (((const int*)mask)[1] != 0) mode = 1;
  else mode = 2;
  int cnt = 0;
  for (int s = lane; s < S_; s += 64) {
    int v;
    if (mode == 0)      v = mb[b*S_ + s] ? 1 : 0;
    else if (mode == 1) v = ((const int*)mask)[b*S_ + s] ? 1 : 0;
    else                v = ((const long long*)mask)[b*S_ + s] ? 1 : 0;
    cnt += v;
  }
  for (int off = 32; off; off >>= 1) cnt += __shfl_xor(cnt, off);
  if (lane == 0) lengths[b] = cnt;
}

// -------- qvec = q_state @ W_q --------
__global__ void k_qvec(const float* __restrict__ qs, const float* __restrict__ Wq,
                       float* __restrict__ qvec) {
  __shared__ float qsl[ENC_];
  int t = threadIdx.x;
  if (t < ENC_) qsl[t] = qs[t];
  __syncthreads();
  if (t < ENC_) {
    float acc = 0.f;
    for (int i = 0; i < ENC_; ++i) acc += qsl[i] * Wq[(size_t)i*ENC_ + t];
    qvec[t] = acc;
  }
}

// -------- wkq[e][head] --------
__global__ void k_wkq(const float* __restrict__ Wk, const float* __restrict__ qvec,
                      float* __restrict__ wkq) {
  int t = threadIdx.x;
  int e = blockIdx.x*64 + (t >> 2);
  int head = t & 3;
  if (e < ENC_) {
    float acc = 0.f;
    const float* row = Wk + (size_t)e*ENC_ + head*100;
    const float* qv  = qvec + head*100;
    for (int d = 0; d < 100; ++d) acc += row[d]*qv[d];
    wkq[e*4 + head] = acc;
  }
}

// -------- input projections via fp16 MFMA (unchanged, passing) --------
__global__ __launch_bounds__(256) void k_gemm_mfma(
    const int* __restrict__ x, const float* __restrict__ emb,
    const float* __restrict__ wf, const float* __restrict__ wb,
    const float* __restrict__ bf, const float* __restrict__ bb,
    float* __restrict__ xWf, float* __restrict__ xWb)
{
  __shared__ int xid[128];
  __shared__ __align__(16) _Float16 sA[128][40];
  __shared__ __align__(16) _Float16 sB[64][40];
  const int t = threadIdx.x;
  const int row0 = blockIdx.x * 128;
  const int col0 = blockIdx.y * 64;
  if (t < 128) xid[t] = x[row0 + t];
  const int w = t >> 6, lane = t & 63;
  const int wr = w >> 1, wc = w & 1;
  f32x4 acc[4][2] = {};
  const int ar = t >> 1, ah = t & 1;
  const int bc = t >> 2, bq = t & 3;
  const int colg = col0 + bc;
  const float* wsrc = (colg < 800) ? (wf + (size_t)colg*300)
                                   : (wb + (size_t)(colg-800)*300);
  __syncthreads();
  const float* asrc = emb + (size_t)xid[ar]*300;
  for (int kc = 0; kc < 10; ++kc) {
    const int k0 = kc*32;
    {
      const int kb = k0 + ah*16;
      _Float16 tmp[16];
      if (kb + 15 < 300) {
        #pragma unroll
        for (int q = 0; q < 4; ++q) {
          float4 a = *(const float4*)(asrc + kb + 4*q);
          tmp[4*q]  =(_Float16)a.x; tmp[4*q+1]=(_Float16)a.y;
          tmp[4*q+2]=(_Float16)a.z; tmp[4*q+3]=(_Float16)a.w;
        }
      } else {
        #pragma unroll
        for (int i = 0; i < 16; ++i)
          tmp[i] = (_Float16)((kb+i < 300) ? asrc[kb+i] : 0.f);
      }
      *(f16x8*)&sA[ar][ah*16]   = *(f16x8*)&tmp[0];
      *(f16x8*)&sA[ar][ah*16+8] = *(f16x8*)&tmp[8];
    }
    {
      const int kb = k0 + bq*8;
      _Float16 tmp[8];
      if (kb + 7 < 300) {
        #pragma unroll
        for (int q = 0; q < 2; ++q) {
          float4 a = *(const float4*)(wsrc + kb + 4*q);
          tmp[4*q]  =(_Float16)a.x; tmp[4*q+1]=(_Float16)a.y;
          tmp[4*q+2]=(_Float16)a.z; tmp[4*q+3]=(_Float16)a.w;
        }
      } else {
        #pragma unroll
        for (int i = 0; i < 8; ++i)
          tmp[i] = (_Float16)((kb+i < 300) ? wsrc[kb+i] : 0.f);
      }
      *(f16x8*)&sB[bc][bq*8] = *(f16x8*)&tmp[0];
    }
    __syncthreads();
    const int fr = lane & 15, kg = lane >> 4;
    f16x8 b0 = *(const f16x8*)&sB[wc*32 + fr][kg*8];
    f16x8 b1 = *(const f16x8*)&sB[wc*32 + 16 + fr][kg*8];
    #pragma unroll
    for (int m = 0; m < 4; ++m) {
      f16x8 afrag = *(const f16x8*)&sA[wr*64 + m*16 + fr][kg*8];
      acc[m][0] = __builtin_amdgcn_mfma_f32_16x16x32_f16(afrag, b0, acc[m][0], 0,0,0);
      acc[m][1] = __builtin_amdgcn_mfma_f32_16x16x32_f16(afrag, b1, acc[m][1], 0,0,0);
    }
    __syncthreads();
  }
  const int crb = (lane >> 4) * 4, ccol = lane & 15;
  #pragma unroll
  for (int n = 0; n < 2; ++n) {
    int colg2 = col0 + wc*32 + n*16 + ccol;
    bool isF = colg2 < 800;
    int colo = isF ? colg2 : colg2 - 800;
    float bias = isF ? bf[colo] : bb[colo];
    float* dst = isF ? xWf : xWb;
    #pragma unroll
    for (int m = 0; m < 4; ++m) {
      int row = row0 + wr*64 + m*16 + crb;
      #pragma unroll
      for (int r = 0; r < 4; ++r)
        dst[(size_t)(row+r)*800 + colo] = acc[m][n][r] + bias;
    }
  }
}

// -------- fallback LSTM (round-4 v2, measured 678 us, known-good) --------
__global__ __launch_bounds__(1024) void k_lstm_v2(
    const float* __restrict__ xWf, const float* __restrict__ xWb,
    const float* __restrict__ whhf, const float* __restrict__ whhb,
    const int* __restrict__ lengths,
    float* __restrict__ h_f, float* __restrict__ h_b)
{
  const int bid = blockIdx.x;
  const int dir = bid >> 5, b = bid & 31;
  const float* __restrict__ xW  = dir ? xWb : xWf;
  const float* __restrict__ whh = dir ? whhb : whhf;
  float* __restrict__ hout      = dir ? h_b : h_f;
  const int len = lengths[b];
  const int t = threadIdx.x;
  const int active = (t < G4_);

  __shared__ __align__(16) _Float16 hbh[200];
  __shared__ float gact[G4_];

  half2v w[100];
  if (active) {
    const float* rp = whh + (size_t)t*H_;
    #pragma unroll
    for (int j = 0; j < 50; ++j) {
      float2 a = *(const float2*)(rp + 2*j);
      w[j] = half2v{(_Float16)a.x, (_Float16)a.y};
    }
    #pragma unroll
    for (int j = 0; j < 50; ++j) {
      float2 a = *(const float2*)(rp + 100 + 2*j);
      w[50+j] = half2v{(_Float16)a.x, (_Float16)a.y};
    }
  }
  if (t < 200) hbh[t] = (_Float16)0.f;
  float cst = 0.f;
  const float* xbase = xW + (size_t)b*S_*G4_;
  const int isTanh = (t >= 400) && (t < 600);
  __syncthreads();

  for (int step = 0; step < len; ++step) {
    const int pos = dir ? (len-1-step) : step;
    if (active) {
      float xv = xbase[(size_t)pos*G4_ + t];
      float a0 = 0.f, a1 = 0.f;
      #pragma unroll
      for (int j = 0; j < 12; ++j) {
        float4 h4 = *(const float4*)&hbh[8*j];
        a0 = FDOT2(w[4*j],   __builtin_bit_cast(half2v, h4.x), a0);
        a1 = FDOT2(w[4*j+1], __builtin_bit_cast(half2v, h4.y), a1);
        a0 = FDOT2(w[4*j+2], __builtin_bit_cast(half2v, h4.z), a0);
        a1 = FDOT2(w[4*j+3], __builtin_bit_cast(half2v, h4.w), a1);
      }
      {
        float2 h2 = *(const float2*)&hbh[96];
        a0 = FDOT2(w[48], __builtin_bit_cast(half2v, h2.x), a0);
        a1 = FDOT2(w[49], __builtin_bit_cast(half2v, h2.y), a1);
      }
      #pragma unroll
      for (int j = 0; j < 12; ++j) {
        float4 h4 = *(const float4*)&hbh[100 + 8*j];
        a0 = FDOT2(w[50+4*j],   __builtin_bit_cast(half2v, h4.x), a0);
        a1 = FDOT2(w[50+4*j+1], __builtin_bit_cast(half2v, h4.y), a1);
        a0 = FDOT2(w[50+4*j+2], __builtin_bit_cast(half2v, h4.z), a0);
        a1 = FDOT2(w[50+4*j+3], __builtin_bit_cast(half2v, h4.w), a1);
      }
      {
        float2 h2 = *(const float2*)&hbh[196];
        a0 = FDOT2(w[98], __builtin_bit_cast(half2v, h2.x), a0);
        a1 = FDOT2(w[99], __builtin_bit_cast(half2v, h2.y), a1);
      }
      float pre = a0 + a1 + xv;
      float act;
      if (isTanh) {
        float gc = fminf(fmaxf(pre, -10.f), 10.f);
        float e2 = __expf(2.f*gc);
        act = (e2-1.f)/(e2+1.f);
      } else {
        act = 1.f/(1.f+__expf(-pre));
      }
      gact[t] = act;
    }
    __syncthreads();
    if (t < 200) {
      float ig = gact[t], fg = gact[200+t], gg = gact[400+t], og = gact[600+t];
      cst = fg*cst + ig*gg;
      float cc = fminf(fmaxf(cst, -10.f), 10.f);
      float ec = __expf(2.f*cc);
      float hn = og*((ec-1.f)/(ec+1.f));
      hout[((size_t)b*S_ + pos)*H_ + t] = hn;
      hbh[t] = (_Float16)hn;
    }
    __syncthreads();
  }
}

// -------- MFMA LSTM: M=1 matvec on the matrix pipe --------
// 64 WGs (one per dir,b chain) x 512 thr (8 waves; launch_bounds(512,1) ->
// 2 waves/SIMD -> 256-reg unified budget). Weights live as MFMA B-fragments
// (~196 regs/thread, AGPR-native operands). h is REPLICATED into all 16
// A-rows by reading hbh with addr = f(lane>>4) only -> one 4-way-multicast
// ds_read_b128 per K-frag builds A with every row = h; C row0 = h . W.
// Frag math: mfma_f32_16x16x32_f16; K=200 padded to 224 (7 frags, B pads
// zeroed, hbh padded with zeros); N=800 = 50 col-frags, wave w owns frags
// f = 8i+w (<50): waves 0,1: 7 frags, waves 2-7: 6.
// Per step: [t<200: issue xW loads] -> 7 A-reads -> <=49 MFMAs -> lanes 0-15
// write C row0 (raw preacts) to gact -> barrier -> t<200 tail: gates+c/h,
// publish h (fp16 LDS + fp32 global) -> barrier.
__global__ __launch_bounds__(512, 1) void k_lstm_mfma(
    const float* __restrict__ xWf, const float* __restrict__ xWb,
    const float* __restrict__ whhf, const float* __restrict__ whhb,
    const int* __restrict__ lengths,
    float* __restrict__ h_f, float* __restrict__ h_b)
{
  const int bid = blockIdx.x;
  const int dir = bid >> 5, b = bid & 31;
  const float* __restrict__ xW  = dir ? xWb : xWf;
  const float* __restrict__ whh = dir ? whhb : whhf;
  float* __restrict__ hout      = dir ? h_b : h_f;
  const int len = lengths[b];
  const int t = threadIdx.x;
  const int w = t >> 6, lane = t & 63;
  const int c16 = lane & 15, kq = lane >> 4;

  __shared__ __align__(16) _Float16 hbh[224];   // h fp16, k padded 200->224 (pad stays 0)
  __shared__ float gact[G4_];                   // raw gate preacts (cols 0..799)

  // ---- one-time B-frag preload: bfrag[i][kf], frag f = 8i+w, col = 16f+c16,
  //      k = 32kf + 8kq + j ; zero outside (f<50, k<200). ----
  f16x8 bfrag[7][7];
  #pragma unroll
  for (int i = 0; i < 7; ++i) {
    const int f = 8*i + w;
    const bool fv = (f < 50);
    const float* wr = whh + (size_t)(fv ? (16*f + c16) : 0) * H_;
    #pragma unroll
    for (int kf = 0; kf < 7; ++kf) {
      f16x8 v;
      #pragma unroll
      for (int j = 0; j < 8; ++j) {
        const int k = 32*kf + 8*kq + j;
        v[j] = (_Float16)((fv && k < 200) ? wr[k] : 0.f);
      }
      bfrag[i][kf] = v;
    }
  }

  for (int i = t; i < 224; i += 512) hbh[i] = (_Float16)0.f;
  float cst = 0.f;
  const float* xbase = xW + (size_t)b*S_*G4_;
  __syncthreads();

  for (int step = 0; step < len; ++step) {
    const int pos = dir ? (len-1-step) : step;
    // prefetch xW gate inputs for tail threads (consumed after barrier)
    float xi = 0.f, xf_ = 0.f, xg = 0.f, xo = 0.f;
    if (t < H_) {
      const float* xr = xbase + (size_t)pos*G4_ + t;
      xi = xr[0]; xf_ = xr[H_]; xg = xr[2*H_]; xo = xr[3*H_];
    }
    // A-frags: addr depends only on kq -> every A-row = h (4-way multicast read)
    f16x8 afr[7];
    #pragma unroll
    for (int kf = 0; kf < 7; ++kf)
      afr[kf] = *(const f16x8*)&hbh[32*kf + 8*kq];
    // MFMA chains per owned N-frag; extract C row0 (lanes 0-15, reg 0)
    #pragma unroll
    for (int i = 0; i < 7; ++i) {
      const int f = 8*i + w;
      if (f < 50) {
        f32x4 acc = {};
        #pragma unroll
        for (int kf = 0; kf < 7; ++kf)
          acc = __builtin_amdgcn_mfma_f32_16x16x32_f16(afr[kf], bfrag[i][kf], acc, 0,0,0);
        if (lane < 16) gact[16*f + lane] = acc[0];
      }
    }
    __syncthreads();
    if (t < H_) {
      float gi = gact[t]        + xi;
      float gf = gact[H_ + t]   + xf_;
      float gg = gact[2*H_ + t] + xg;
      float go = gact[3*H_ + t] + xo;
      float ig = 1.f/(1.f+__expf(-gi));
      float fg = 1.f/(1.f+__expf(-gf));
      float og = 1.f/(1.f+__expf(-go));
      float ggc = fminf(fmaxf(gg, -10.f), 10.f);
      float eg = __expf(2.f*ggc);
      cst = fg*cst + ig*((eg-1.f)/(eg+1.f));
      float cc = fminf(fmaxf(cst, -10.f), 10.f);
      float ec = __expf(2.f*cc);
      float hn = og*((ec-1.f)/(ec+1.f));
      hout[((size_t)b*S_ + pos)*H_ + t] = hn;
      hbh[t] = (_Float16)hn;
    }
    __syncthreads();
  }
}

// -------- scores --------
__global__ __launch_bounds__(256) void k_scores(
    const float* __restrict__ hf, const float* __restrict__ hb,
    const float* __restrict__ wkq, const int* __restrict__ lengths,
    float* __restrict__ theta)
{
  int wid = blockIdx.x*4 + (threadIdx.x >> 6);
  int lane = threadIdx.x & 63;
  int b = wid >> 9, s = wid & 511;
  const float* hfr = hf + ((size_t)b*S_ + s)*H_;
  const float* hbr = hb + ((size_t)b*S_ + s)*H_;
  bool valid = s < lengths[b];
  float a0=0.f, a1=0.f, a2=0.f, a3=0.f;
  if (valid) {
    for (int e = lane; e < ENC_; e += 64) {
      float hv = (e < H_) ? hfr[e] : hbr[e-H_];
      float4 w = *(const float4*)(wkq + e*4);
      a0 += hv*w.x; a1 += hv*w.y; a2 += hv*w.z; a3 += hv*w.w;
    }
    for (int off = 32; off; off >>= 1) {
      a0 += __shfl_xor(a0, off); a1 += __shfl_xor(a1, off);
      a2 += __shfl_xor(a2, off); a3 += __shfl_xor(a3, off);
    }
  }
  if (lane == 0) {
    size_t base = (size_t)b*2048 + s;
    theta[base       ] = valid ? SCALE_*a0 : NEGV;
    theta[base +  512] = valid ? SCALE_*a1 : NEGV;
    theta[base + 1024] = valid ? SCALE_*a2 : NEGV;
    theta[base + 1536] = valid ? SCALE_*a3 : NEGV;
  }
}

// -------- sparseMAP budget projection --------
__global__ void k_sparsemap(const float* __restrict__ theta, const int* __restrict__ lengths,
                            float* __restrict__ mu) {
  int pid = blockIdx.x;
  int lane = threadIdx.x;
  const float* th = theta + (size_t)pid*512;
  float v[8];
  #pragma unroll
  for (int i = 0; i < 8; ++i) v[i] = th[i*64 + lane];
  float kf = rintf(0.2f * (float)lengths[pid >> 2]);
  float mn = v[0], mx = v[0];
  #pragma unroll
  for (int i = 1; i < 8; ++i) { mn = fminf(mn, v[i]); mx = fmaxf(mx, v[i]); }
  for (int off = 32; off; off >>= 1) {
    mn = fminf(mn, __shfl_xor(mn, off)); mx = fmaxf(mx, __shfl_xor(mx, off));
  }
  float lo = mn - 1.f, hi = mx;
  for (int it = 0; it < 60; ++it) {
    float mid = 0.5f*(lo + hi);
    float s = 0.f;
    #pragma unroll
    for (int i = 0; i < 8; ++i) s += fminf(fmaxf(v[i]-mid, 0.f), 1.f);
    for (int off = 32; off; off >>= 1) s += __shfl_xor(s, off);
    bool big = s > kf;
    lo = big ? mid : lo;
    hi = big ? hi : mid;
  }
  float tau0 = 0.5f*(lo + hi);
  float fs = 0.f, nU = 0.f, nS = 0.f;
  #pragma unroll
  for (int i = 0; i < 8; ++i) {
    float m0 = v[i] - tau0;
    if (m0 >= 1.f) nU += 1.f;
    else if (m0 > 0.f) { fs += v[i]; nS += 1.f; }
  }
  for (int off = 32; off; off >>= 1) {
    fs += __shfl_xor(fs, off); nU += __shfl_xor(nU, off); nS += __shfl_xor(nS, off);
  }
  float tau = (fs + nU - kf) / fmaxf(nS, 1.f);
  tau = (nS > 0.f) ? tau : tau0;
  float* mo = mu + (size_t)pid*512;
  #pragma unroll
  for (int i = 0; i < 8; ++i) mo[i*64 + lane] = fminf(fmaxf(v[i]-tau, 0.f), 1.f);
}

// -------- hp[b,head,e] = sum_s mu * h --------
__global__ __launch_bounds__(512) void k_hp(
    const float* __restrict__ mu, const float* __restrict__ hf,
    const float* __restrict__ hb, float* __restrict__ hp)
{
  __shared__ float mul[512];
  int pid = blockIdx.x, b = pid >> 2;
  int t = threadIdx.x;
  mul[t] = mu[(size_t)pid*512 + t];
  __syncthreads();
  if (t < ENC_) {
    const float* hsrc = (t < H_) ? (hf + t) : (hb + (t - H_));
    float acc = 0.f;
    for (int s = 0; s < 512; ++s) {
      float m = mul[s];
      if (m != 0.f) acc += m * hsrc[((size_t)b*S_ + s)*H_];
    }
    hp[(size_t)pid*ENC_ + t] = acc;
  }
}

// -------- head --------
__global__ __launch_bounds__(512) void k_head(
    const float* __restrict__ hp, const float* __restrict__ Wv,
    const float* __restrict__ Wout, const float* __restrict__ Wh,
    const float* __restrict__ bh, float* __restrict__ out)
{
  __shared__ float hpl[1600];
  __shared__ float ppl[ENC_];
  __shared__ float ojl[ENC_];
  __shared__ float red[512];
  int b = blockIdx.x, t = threadIdx.x;
  for (int i = t; i < 1600; i += 512) hpl[i] = hp[(size_t)b*1600 + i];
  __syncthreads();
  if (t < ENC_) {
    int head = t / 100;
    float acc = 0.f;
    for (int e = 0; e < ENC_; ++e) acc += hpl[head*ENC_ + e] * Wv[(size_t)e*ENC_ + t];
    ppl[t] = acc;
  }
  __syncthreads();
  if (t < ENC_) {
    float acc = 0.f;
    for (int c = 0; c < ENC_; ++c) acc += ppl[c] * Wout[(size_t)c*ENC_ + t];
    ojl[t] = acc;
  }
  __syncthreads();
  red[t] = (t < ENC_) ? ojl[t]*Wh[t] : 0.f;
  __syncthreads();
  for (int sft = 256; sft; sft >>= 1) {
    if (t < sft) red[t] += red[t+sft];
    __syncthreads();
  }
  if (t == 0) out[b] = 1.f/(1.f + expf(-(red[0] + bh[0])));
}

// -------- z --------
__global__ void k_z(const float* __restrict__ mu, const int* __restrict__ lengths,
                    float* __restrict__ out) {
  int idx = blockIdx.x*256 + threadIdx.x;
  int b = idx >> 9, s = idx & 511;
  float zz = 0.f;
  if (s < lengths[b]) {
    size_t base = (size_t)b*2048 + s;
    zz = 0.25f*(mu[base] + mu[base+512] + mu[base+1024] + mu[base+1536]);
  }
  out[32 + idx] = zz;
}

extern "C" void kernel_launch(void* const* d_in, const int* in_sizes, int n_in,
                              void* d_out, int out_size, void* d_ws, size_t ws_size,
                              hipStream_t stream) {
  const int*   x    = (const int*)d_in[0];
  const void*  mask = d_in[1];
  const float* emb  = (const float*)d_in[2];
  const float* wihf = (const float*)d_in[3];
  const float* whhf = (const float*)d_in[4];
  const float* bf   = (const float*)d_in[5];
  const float* wihb = (const float*)d_in[6];
  const float* whhb = (const float*)d_in[7];
  const float* bb   = (const float*)d_in[8];
  const float* qs   = (const float*)d_in[9];
  const float* Wq   = (const float*)d_in[10];
  const float* Wk   = (const float*)d_in[11];
  const float* Wv   = (const float*)d_in[12];
  const float* Wout = (const float*)d_in[13];
  const float* Wh   = (const float*)d_in[14];
  const float* bh   = (const float*)d_in[15];
  float* out = (float*)d_out;
  float* W = (float*)d_ws;
  int* lengths = (int*)(W + OF_LEN);

  // Gate: use the MFMA LSTM only if the compiler kept its ~236-reg demand
  // fully in the unified register file (no scratch). Host-only query,
  // deterministic, graph-capture safe.
  hipFuncAttributes fa{};
  bool use_mfma = false;
  if (hipFuncGetAttributes(&fa, (const void*)k_lstm_mfma) == hipSuccess)
    use_mfma = (fa.localSizeBytes <= 64);

  k_lengths<<<32, 64, 0, stream>>>(mask, lengths);
  k_qvec<<<1, 512, 0, stream>>>(qs, Wq, W+OF_QVEC);
  k_wkq<<<7, 256, 0, stream>>>(Wk, W+OF_QVEC, W+OF_WKQ);
  k_gemm_mfma<<<dim3(128, 25), 256, 0, stream>>>(x, emb, wihf, wihb, bf, bb,
                                                 W+OF_XWF, W+OF_XWB);
  if (use_mfma)
    k_lstm_mfma<<<64, 512, 0, stream>>>(W+OF_XWF, W+OF_XWB, whhf, whhb,
                                        lengths, W+OF_HF, W+OF_HB);
  else
    k_lstm_v2<<<64, 1024, 0, stream>>>(W+OF_XWF, W+OF_XWB, whhf, whhb,
                                       lengths, W+OF_HF, W+OF_HB);
  k_scores<<<4096, 256, 0, stream>>>(W+OF_HF, W+OF_HB, W+OF_WKQ, lengths, W+OF_THETA);
  k_sparsemap<<<128, 64, 0, stream>>>(W+OF_THETA, lengths, W+OF_MU);
  k_hp<<<128, 512, 0, stream>>>(W+OF_MU, W+OF_HF, W+OF_HB, W+OF_HP);
  k_head<<<32, 512, 0, stream>>>(W+OF_HP, Wv, Wout, Wh, bh, out);
  k_z<<<64, 256, 0, stream>>>(W+OF_MU, lengths, out);
}